// Round 5
// baseline (249.928 us; speedup 1.0000x reference)
//
#include <hip/hip_runtime.h>
#include <hip/hip_bf16.h>

// QJL with orthogonal projections, MI355X (gfx950).
// out[t] = scale * sum_m sign(K[t]·S[m]) * (Q[t]·S[m]),  t in [0,131072)
//
// Single kernel:
//  - Transposed MFMA GEMM (m on MFMA-M, tokens on MFMA-N), 16x16x32 bf16.
//  - C = K·S^T via 3-pass bf16 hi/lo split (dot err sigma ~1e-4);
//    QP = Q·S^T via 1-pass bf16 (out err max ~0.012, threshold 0.096).
//  - S hi/lo A-fragments converted in-kernel from fp32 S, persistent in regs.
//  - |C| < TAU -> sign re-arbitrated by an fp32 dot emulating the reference's
//    BLAS path: np einsum-optimize/tensordot/matmul -> cblas_sgemm (OpenBLAS
//    microkernel) = ONE accumulator per C element, vfmadd231ps over k
//    STRICTLY ASCENDING, K=128 < KC so unblocked. We replicate it with a
//    sequential fp32 FMA chain (v_fma_f32 == IEEE FMA == x86 FMA3 bitwise).
//    np.sign(0) = 0 honored.
//  - Cross-wave combine via LDS; each out token stored exactly once.

#define DIM        128
#define NPROJ      256
#define NTOK       131072      // 2*16*4096
#define TILE_T     32          // tokens per tile
#define NWG        512
#define TPW        8           // tiles per workgroup: NTOK/TILE_T/NWG
#define LDS_STRIDE 136         // 128 + 8 bf16 pad (16B-aligned rows, 2-way-free banks)
#define TAU        6.0e-3f     // ~60 sigma of the 3-pass dot error
#define SCALE      0.0048957583489668f  // sqrt(pi/2)/256

typedef __attribute__((ext_vector_type(8))) short short8;  // 8 bf16 = 4 VGPRs
typedef __attribute__((ext_vector_type(4))) float f32x4;

static __device__ __forceinline__ unsigned short bf16_rne(float x){
    unsigned int u = __builtin_bit_cast(unsigned int, x);
    u += 0x7FFFu + ((u >> 16) & 1u);          // round-to-nearest-even
    return (unsigned short)(u >> 16);
}

// Sign arbiter for ambiguous dots: emulates OpenBLAS sgemm's per-element
// k-chain — acc = fma(k[d], s[d], acc), d ascending 0..127, fp32, single
// rounding per step (exact IEEE FMA on both ISAs). Returns
// (s_ref - s_used) * qp  in {0, +-qp, +-2qp}.
static __device__ __attribute__((noinline))
float sign_fix_delta(const float* __restrict__ Kg, const float* __restrict__ S,
                     int tok, int m, float c, float qp){
    const float* kr = Kg + (size_t)tok * DIM;
    const float* sr = S  + (size_t)m   * DIM;
    float acc = 0.f;
#pragma unroll 8
    for (int d = 0; d < DIM; ++d){
        acc = __builtin_fmaf(kr[d], sr[d], acc);
    }
    float s_used = (c >= 0.f) ? 1.f : -1.f;
    float s_ref  = (acc > 0.f) ? 1.f : ((acc < 0.f) ? -1.f : 0.f);  // np.sign(0)=0
    return (s_ref - s_used) * qp;
}

__global__ __launch_bounds__(256, 2)
void qjl_main(const float* __restrict__ Qg, const float* __restrict__ Kg,
              const float* __restrict__ S, float* __restrict__ out)
{
    // Token tiles in LDS (m97-style row-major, stride 136 bf16).
    __shared__ unsigned short khi[TILE_T * LDS_STRIDE];
    __shared__ unsigned short klo[TILE_T * LDS_STRIDE];
    __shared__ unsigned short qhi[TILE_T * LDS_STRIDE];
    __shared__ float red[4][TILE_T];           // cross-wave combine

    const int tid  = threadIdx.x;
    const int wave = tid >> 6;          // 4 waves: m-windows of 64
    const int lane = tid & 63;
    const int l16  = lane & 15;
    const int quad = lane >> 4;
    const int mwin = wave * 64;

    // ---- register prefetch of tile 0 (K and Q fp32, coalesced float4) ----
    float4 kpre[4], qpre[4];
    {
        const float4* ksrc = (const float4*)(Kg + (size_t)blockIdx.x * TILE_T * DIM);
        const float4* qsrc = (const float4*)(Qg + (size_t)blockIdx.x * TILE_T * DIM);
#pragma unroll
        for (int j = 0; j < 4; ++j){ kpre[j] = ksrc[tid + j*256]; qpre[j] = qsrc[tid + j*256]; }
    }

    // ---- persistent A-fragments: S hi/lo for this wave's 64-m window ----
    // A-frag layout (16x16x32): A[row=lane&15][k=quad*8+j]  [m89/m120-verified]
    short8 a_hi[4][4], a_lo[4][4];
#pragma unroll
    for (int ms = 0; ms < 4; ++ms){
#pragma unroll
        for (int ks = 0; ks < 4; ++ks){
            const float4* p = (const float4*)(S + (size_t)(mwin + ms*16 + l16)*DIM
                                              + ks*32 + quad*8);
            float4 x0 = p[0], x1 = p[1];
            float xs[8] = {x0.x,x0.y,x0.z,x0.w, x1.x,x1.y,x1.z,x1.w};
            short8 h, l;
#pragma unroll
            for (int e = 0; e < 8; ++e){
                unsigned short hb = bf16_rne(xs[e]);
                float hf = __builtin_bit_cast(float, (unsigned int)hb << 16);
                h[e] = (short)hb;
                l[e] = (short)bf16_rne(xs[e] - hf);
            }
            a_hi[ms][ks] = h;
            a_lo[ms][ks] = l;
        }
    }

    for (int t = 0; t < TPW; ++t){
        const int tile = blockIdx.x + t * NWG;

        // ---- stage prefetched fp32 -> bf16 hi/lo tiles in LDS ----
#pragma unroll
        for (int j = 0; j < 4; ++j){
            int i   = tid + j*256;     // float4 index within tile
            int row = i >> 5;          // token row 0..31
            int c   = i & 31;          // float4 column (d = 4c)
            float kx[4] = {kpre[j].x, kpre[j].y, kpre[j].z, kpre[j].w};
            float qx[4] = {qpre[j].x, qpre[j].y, qpre[j].z, qpre[j].w};
            unsigned long long hp = 0, lp = 0, qp = 0;
#pragma unroll
            for (int e = 0; e < 4; ++e){
                unsigned short hb = bf16_rne(kx[e]);
                float hf = __builtin_bit_cast(float, (unsigned int)hb << 16);
                hp |= (unsigned long long)hb                   << (16*e);
                lp |= (unsigned long long)bf16_rne(kx[e] - hf) << (16*e);
                qp |= (unsigned long long)bf16_rne(qx[e])      << (16*e);
            }
            int base = row * LDS_STRIDE + c*4;    // 8B-aligned
            *(unsigned long long*)(khi + base) = hp;
            *(unsigned long long*)(klo + base) = lp;
            *(unsigned long long*)(qhi + base) = qp;
        }
        __syncthreads();

        // ---- issue prefetch for next tile (hidden under the MFMA loop) ----
        if (t + 1 < TPW){
            const size_t nb = (size_t)(blockIdx.x + (t+1)*NWG) * TILE_T * DIM;
            const float4* ksrc = (const float4*)(Kg + nb);
            const float4* qsrc = (const float4*)(Qg + nb);
#pragma unroll
            for (int j = 0; j < 4; ++j){ kpre[j] = ksrc[tid + j*256]; qpre[j] = qsrc[tid + j*256]; }
        }

        // ---- K-loop: C^T (3-pass) and QP^T (1-pass), 64m x 32tok per wave ----
        f32x4 accC[4][2], accQ[4][2];
#pragma unroll
        for (int ms = 0; ms < 4; ++ms)
#pragma unroll
            for (int ts = 0; ts < 2; ++ts){
                accC[ms][ts] = (f32x4){0.f,0.f,0.f,0.f};
                accQ[ms][ts] = (f32x4){0.f,0.f,0.f,0.f};
            }

#pragma unroll
        for (int ks = 0; ks < 4; ++ks){
#pragma unroll
            for (int ts = 0; ts < 2; ++ts){
                // B-frag layout: B[k=quad*8+j][n=lane&15]; LDS row = token
                const int off = (ts*16 + l16) * LDS_STRIDE + ks*32 + quad*8;
                short8 bk = *(const short8*)(khi + off);
                short8 bl = *(const short8*)(klo + off);
                short8 bq = *(const short8*)(qhi + off);
#pragma unroll
                for (int ms = 0; ms < 4; ++ms){
                    accC[ms][ts] = __builtin_amdgcn_mfma_f32_16x16x32_bf16(a_hi[ms][ks], bk, accC[ms][ts], 0,0,0);
                    accC[ms][ts] = __builtin_amdgcn_mfma_f32_16x16x32_bf16(a_lo[ms][ks], bk, accC[ms][ts], 0,0,0);
                    accC[ms][ts] = __builtin_amdgcn_mfma_f32_16x16x32_bf16(a_hi[ms][ks], bl, accC[ms][ts], 0,0,0);
                    accQ[ms][ts] = __builtin_amdgcn_mfma_f32_16x16x32_bf16(a_hi[ms][ks], bq, accQ[ms][ts], 0,0,0);
                }
            }
        }

        // ---- epilogue: C/D layout col=lane&15 (token), row=quad*4+reg (m) ----
        const int tok0 = tile * TILE_T;
        float part0 = 0.f, part1 = 0.f;
#pragma unroll
        for (int ts = 0; ts < 2; ++ts){
#pragma unroll
            for (int ms = 0; ms < 4; ++ms){
#pragma unroll
                for (int r = 0; r < 4; ++r){
                    float c  = accC[ms][ts][r];
                    float qp = accQ[ms][ts][r];
                    float sv = (c >= 0.f) ? qp : -qp;
                    if (__builtin_fabsf(c) < TAU){   // ambiguous: BLAS-chain arbiter
                        sv += sign_fix_delta(Kg, S,
                                             tok0 + ts*16 + l16,
                                             mwin + ms*16 + quad*4 + r,
                                             c, qp);
                    }
                    if (ts) part1 += sv; else part0 += sv;
                }
            }
        }
        // token t lives in lanes l16, l16+16, l16+32, l16+48 -> 2-step butterfly
        part0 += __shfl_xor(part0, 16, 64);
        part0 += __shfl_xor(part0, 32, 64);
        part1 += __shfl_xor(part1, 16, 64);
        part1 += __shfl_xor(part1, 32, 64);
        if (quad == 0){
            red[wave][l16]      = part0;
            red[wave][16 + l16] = part1;
        }
        __syncthreads();
        if (tid < TILE_T){
            float s = red[0][tid] + red[1][tid] + red[2][tid] + red[3][tid];
            out[tok0 + tid] = SCALE * s;
        }
        __syncthreads();   // protect LDS (tiles + red) before next iteration
    }
}

extern "C" void kernel_launch(void* const* d_in, const int* in_sizes, int n_in,
                              void* d_out, int out_size, void* d_ws, size_t ws_size,
                              hipStream_t stream){
    const float* Qg = (const float*)d_in[0];
    const float* Kg = (const float*)d_in[1];
    const float* S  = (const float*)d_in[2];
    float* out = (float*)d_out;
    (void)d_ws; (void)ws_size;

    qjl_main<<<NWG, 256, 0, stream>>>(Qg, Kg, S, out);
}

// Round 6
// 205.503 us; speedup vs baseline: 1.2162x; 1.2162x over previous
//
#include <hip/hip_runtime.h>
#include <hip/hip_bf16.h>

// QJL with orthogonal projections, MI355X (gfx950).
// out[t] = scale * sum_m sign(K[t]·S[m]) * (Q[t]·S[m]),  t in [0,131072)
//
// R6 structure (post-spill fix):
//  - 4096 wgs x 256 thr, one 32-token tile each. No persistent fragments.
//  - prep kernel: S -> bf16 hi/lo tables in d_ws, PRE-SWIZZLED into MFMA
//    A-fragment order (per (wave,ks,ms): 64 lanes x 16 B contiguous) so the
//    main loop's S loads are single coalesced dwordx4 from L2.
//  - Loop 1: C = K·S^T (3-pass bf16 hi/lo MFMA) -> per-lane 32-bit sign mask;
//    |C| < TAU resolved immediately by the proven OpenBLAS-chain arbiter
//    (sequential ascending fp32 FMA; np.sign(0)=0 -> zero mask).
//  - Loop 2: QP = Q·S^T (1-pass) -> apply signs, wave butterfly + LDS
//    cross-wave combine, one store per token.
//  - Peak live acc = 32 VGPRs per loop (was 64) + no persistent S frags
//    -> fits __launch_bounds__(256,4) without scratch spill.

#define DIM        128
#define NPROJ      256
#define TILE_T     32
#define NWG        4096        // NTOK / TILE_T
#define LDS_STRIDE 136         // bf16 elems; m97-proven padded layout
#define TAU        6.0e-3f
#define SCALE      0.0048957583489668f  // sqrt(pi/2)/256

typedef __attribute__((ext_vector_type(8))) short short8;  // 8 bf16 = 4 VGPRs
typedef __attribute__((ext_vector_type(4))) float f32x4;

static __device__ __forceinline__ unsigned short bf16_rne(float x){
    unsigned int u = __builtin_bit_cast(unsigned int, x);
    u += 0x7FFFu + ((u >> 16) & 1u);
    return (unsigned short)(u >> 16);
}

// Reference-exact sign: OpenBLAS sgemm per-element k-chain, fp32 FMA,
// ascending d. Returns np.sign(dot) in {-1, 0, +1}.  [verified round 5]
static __device__ __attribute__((noinline))
float ref_sign(const float* __restrict__ Kg, const float* __restrict__ S,
               int tok, int m){
    const float* kr = Kg + (size_t)tok * DIM;
    const float* sr = S  + (size_t)m   * DIM;
    float acc = 0.f;
#pragma unroll 8
    for (int d = 0; d < DIM; ++d)
        acc = __builtin_fmaf(kr[d], sr[d], acc);
    return (acc > 0.f) ? 1.f : ((acc < 0.f) ? -1.f : 0.f);
}

// S -> bf16 hi/lo, swizzled to fragment order:
//   tab[(((g*4+ks)*4+ms)*64 + lane)*8 + e] = conv(S[g*64+ms*16+(lane&15)]
//                                                  [ks*32+(lane>>4)*8+e])
__global__ void prep_s_kernel(const float* __restrict__ S,
                              unsigned short* __restrict__ shi,
                              unsigned short* __restrict__ slo){
    int t    = blockIdx.x * 256 + threadIdx.x;   // 4096 threads
    int lane = t & 63;
    int ms   = (t >> 6) & 3;
    int ks   = (t >> 8) & 3;
    int g    = (t >> 10) & 3;
    int m    = g*64 + ms*16 + (lane & 15);
    int d    = ks*32 + (lane >> 4)*8;
    const float4* p = (const float4*)(S + (size_t)m*DIM + d);
    float4 x0 = p[0], x1 = p[1];
    float xs[8] = {x0.x,x0.y,x0.z,x0.w, x1.x,x1.y,x1.z,x1.w};
    size_t base = ((size_t)t) * 8;
    unsigned long long h0=0,h1=0,l0=0,l1=0;
#pragma unroll
    for (int e = 0; e < 4; ++e){
        unsigned short hb = bf16_rne(xs[e]);
        float hf = __builtin_bit_cast(float, (unsigned int)hb << 16);
        h0 |= (unsigned long long)hb                    << (16*e);
        l0 |= (unsigned long long)bf16_rne(xs[e] - hf)  << (16*e);
    }
#pragma unroll
    for (int e = 0; e < 4; ++e){
        unsigned short hb = bf16_rne(xs[4+e]);
        float hf = __builtin_bit_cast(float, (unsigned int)hb << 16);
        h1 |= (unsigned long long)hb                      << (16*e);
        l1 |= (unsigned long long)bf16_rne(xs[4+e] - hf)  << (16*e);
    }
    *(unsigned long long*)(shi + base)     = h0;
    *(unsigned long long*)(shi + base + 4) = h1;
    *(unsigned long long*)(slo + base)     = l0;
    *(unsigned long long*)(slo + base + 4) = l1;
}

// Load this wave's A-fragments for one ks: table path (coalesced 16B/lane)
// or inline-convert fallback from fp32 S.
template<bool USE_TAB>
static __device__ __forceinline__
void load_afrags(const unsigned short* __restrict__ shi_tab,
                 const unsigned short* __restrict__ slo_tab,
                 const float* __restrict__ S,
                 int wave, int ks, int l16, int quad, int lane,
                 short8 ah[4], short8 al[4], bool need_lo){
    if (USE_TAB){
#pragma unroll
        for (int ms = 0; ms < 4; ++ms){
            size_t off = ((size_t)((wave*4 + ks)*4 + ms)*64 + lane)*8;
            ah[ms] = *(const short8*)(shi_tab + off);
            if (need_lo) al[ms] = *(const short8*)(slo_tab + off);
        }
    } else {
#pragma unroll
        for (int ms = 0; ms < 4; ++ms){
            const float4* p = (const float4*)(S + (size_t)(wave*64 + ms*16 + l16)*DIM
                                              + ks*32 + quad*8);
            float4 x0 = p[0], x1 = p[1];
            float xs[8] = {x0.x,x0.y,x0.z,x0.w, x1.x,x1.y,x1.z,x1.w};
            short8 h, l;
#pragma unroll
            for (int e = 0; e < 8; ++e){
                unsigned short hb = bf16_rne(xs[e]);
                float hf = __builtin_bit_cast(float, (unsigned int)hb << 16);
                h[e] = (short)hb;
                l[e] = (short)bf16_rne(xs[e] - hf);
            }
            ah[ms] = h;
            if (need_lo) al[ms] = l;
        }
    }
}

template<bool USE_TAB>
__global__ __launch_bounds__(256, 4)
void qjl_kernel(const float* __restrict__ Qg, const float* __restrict__ Kg,
                const float* __restrict__ S,
                const unsigned short* __restrict__ shi_tab,
                const unsigned short* __restrict__ slo_tab,
                float* __restrict__ out)
{
    __shared__ unsigned short khi[TILE_T * LDS_STRIDE];
    __shared__ unsigned short klo[TILE_T * LDS_STRIDE];
    __shared__ unsigned short qhi[TILE_T * LDS_STRIDE];
    __shared__ float red[4][TILE_T];

    const int tid  = threadIdx.x;
    const int wave = tid >> 6;
    const int lane = tid & 63;
    const int l16  = lane & 15;
    const int quad = lane >> 4;
    const int tok0 = blockIdx.x * TILE_T;

    // ---- stage: 32 tokens of K and Q, fp32 -> bf16 hi/lo in LDS ----
    {
        const float4* ksrc = (const float4*)(Kg + (size_t)tok0 * DIM);
        const float4* qsrc = (const float4*)(Qg + (size_t)tok0 * DIM);
        float4 kv[4], qv[4];
#pragma unroll
        for (int j = 0; j < 4; ++j){ kv[j] = ksrc[tid + j*256]; qv[j] = qsrc[tid + j*256]; }
#pragma unroll
        for (int j = 0; j < 4; ++j){
            int i   = tid + j*256;
            int row = i >> 5;
            int c   = i & 31;
            float kx[4] = {kv[j].x, kv[j].y, kv[j].z, kv[j].w};
            float qx[4] = {qv[j].x, qv[j].y, qv[j].z, qv[j].w};
            unsigned long long hp = 0, lp = 0, qp = 0;
#pragma unroll
            for (int e = 0; e < 4; ++e){
                unsigned short hb = bf16_rne(kx[e]);
                float hf = __builtin_bit_cast(float, (unsigned int)hb << 16);
                hp |= (unsigned long long)hb                   << (16*e);
                lp |= (unsigned long long)bf16_rne(kx[e] - hf) << (16*e);
                qp |= (unsigned long long)bf16_rne(qx[e])      << (16*e);
            }
            int base = row * LDS_STRIDE + c*4;
            *(unsigned long long*)(khi + base) = hp;
            *(unsigned long long*)(klo + base) = lp;
            *(unsigned long long*)(qhi + base) = qp;
        }
    }
    __syncthreads();

    // ---- loop 1: C = K·S^T (3-pass), compress to sign masks ----
    unsigned int negw = 0, zerow = 0;
    {
        f32x4 accC[4][2];
#pragma unroll
        for (int ms = 0; ms < 4; ++ms)
#pragma unroll
            for (int ts = 0; ts < 2; ++ts)
                accC[ms][ts] = (f32x4){0.f,0.f,0.f,0.f};

#pragma unroll
        for (int ks = 0; ks < 4; ++ks){
            short8 ah[4], al[4];
            load_afrags<USE_TAB>(shi_tab, slo_tab, S, wave, ks, l16, quad, lane,
                                 ah, al, true);
#pragma unroll
            for (int ts = 0; ts < 2; ++ts){
                const int off = (ts*16 + l16) * LDS_STRIDE + ks*32 + quad*8;
                short8 bk = *(const short8*)(khi + off);
                short8 bl = *(const short8*)(klo + off);
#pragma unroll
                for (int ms = 0; ms < 4; ++ms){
                    accC[ms][ts] = __builtin_amdgcn_mfma_f32_16x16x32_bf16(ah[ms], bk, accC[ms][ts], 0,0,0);
                    accC[ms][ts] = __builtin_amdgcn_mfma_f32_16x16x32_bf16(al[ms], bk, accC[ms][ts], 0,0,0);
                    accC[ms][ts] = __builtin_amdgcn_mfma_f32_16x16x32_bf16(ah[ms], bl, accC[ms][ts], 0,0,0);
                }
            }
        }
        // C/D layout: col(token)=lane&15, row(m)=quad*4+r
#pragma unroll
        for (int ts = 0; ts < 2; ++ts){
#pragma unroll
            for (int ms = 0; ms < 4; ++ms){
#pragma unroll
                for (int r = 0; r < 4; ++r){
                    float c = accC[ms][ts][r];
                    float s = (c >= 0.f) ? 1.f : -1.f;
                    if (__builtin_fabsf(c) < TAU)
                        s = ref_sign(Kg, S, tok0 + ts*16 + l16,
                                     wave*64 + ms*16 + quad*4 + r);
                    int bit = (ts*4 + ms)*4 + r;
                    if (s < 0.f)  negw  |= (1u << bit);
                    if (s == 0.f) zerow |= (1u << bit);
                }
            }
        }
    }

    // ---- loop 2: QP = Q·S^T (1-pass), apply signs ----
    float part0 = 0.f, part1 = 0.f;
    {
        f32x4 accQ[4][2];
#pragma unroll
        for (int ms = 0; ms < 4; ++ms)
#pragma unroll
            for (int ts = 0; ts < 2; ++ts)
                accQ[ms][ts] = (f32x4){0.f,0.f,0.f,0.f};

#pragma unroll
        for (int ks = 0; ks < 4; ++ks){
            short8 ah[4], al_unused[4];
            load_afrags<USE_TAB>(shi_tab, slo_tab, S, wave, ks, l16, quad, lane,
                                 ah, al_unused, false);
#pragma unroll
            for (int ts = 0; ts < 2; ++ts){
                const int off = (ts*16 + l16) * LDS_STRIDE + ks*32 + quad*8;
                short8 bq = *(const short8*)(qhi + off);
#pragma unroll
                for (int ms = 0; ms < 4; ++ms)
                    accQ[ms][ts] = __builtin_amdgcn_mfma_f32_16x16x32_bf16(ah[ms], bq, accQ[ms][ts], 0,0,0);
            }
        }
#pragma unroll
        for (int ts = 0; ts < 2; ++ts){
#pragma unroll
            for (int ms = 0; ms < 4; ++ms){
#pragma unroll
                for (int r = 0; r < 4; ++r){
                    float qp = accQ[ms][ts][r];
                    int bit = (ts*4 + ms)*4 + r;
                    float sv = (zerow >> bit) & 1u ? 0.f
                             : ((negw >> bit) & 1u ? -qp : qp);
                    if (ts) part1 += sv; else part0 += sv;
                }
            }
        }
    }

    // ---- reduce: token t in lanes {l16, l16+16, l16+32, l16+48} ----
    part0 += __shfl_xor(part0, 16, 64);
    part0 += __shfl_xor(part0, 32, 64);
    part1 += __shfl_xor(part1, 16, 64);
    part1 += __shfl_xor(part1, 32, 64);
    if (quad == 0){
        red[wave][l16]      = part0;
        red[wave][16 + l16] = part1;
    }
    __syncthreads();
    if (tid < TILE_T)
        out[tok0 + tid] = SCALE * (red[0][tid] + red[1][tid] + red[2][tid] + red[3][tid]);
}

extern "C" void kernel_launch(void* const* d_in, const int* in_sizes, int n_in,
                              void* d_out, int out_size, void* d_ws, size_t ws_size,
                              hipStream_t stream){
    const float* Qg = (const float*)d_in[0];
    const float* Kg = (const float*)d_in[1];
    const float* S  = (const float*)d_in[2];
    float* out = (float*)d_out;

    const size_t tab_elems = (size_t)NPROJ * DIM;        // 32768 per table
    const size_t need = 2 * tab_elems * sizeof(unsigned short);  // 128 KiB

    if (d_ws && ws_size >= need){
        unsigned short* shi = (unsigned short*)d_ws;
        unsigned short* slo = shi + tab_elems;
        prep_s_kernel<<<16, 256, 0, stream>>>(S, shi, slo);
        qjl_kernel<true><<<NWG, 256, 0, stream>>>(Qg, Kg, S, shi, slo, out);
    } else {
        qjl_kernel<false><<<NWG, 256, 0, stream>>>(Qg, Kg, S, nullptr, nullptr, out);
    }
}